// Round 8
// baseline (92.844 us; speedup 1.0000x reference)
//
#include <hip/hip_runtime.h>
#include <math.h>

#define CIN    16
#define COUT   64
#define H      256
#define W      256
#define OH     254
#define OW     254
#define NTAP   9
#define STRIP  32

typedef _Float16 f16x8  __attribute__((ext_vector_type(8)));
typedef float    f32x16 __attribute__((ext_vector_type(16)));

// Bank-spreading bijective slot map within a 128-slot row region.
#define XS(px, g) ((((px) << 1) | (g)) ^ (((px) >> 2) & 7))

// weight pack: [tap 9][msub 2][lane 64][e 8] fp16; co=(l&31)+32m, cin=8*(l>>5)+e
__global__ void wpack_kernel(const float* __restrict__ w, _Float16* __restrict__ wpk) {
    int idx = blockIdx.x * 256 + threadIdx.x;   // 0..9215
    if (idx >= NTAP * 2 * 64 * 8) return;
    int e = idx & 7, l = (idx >> 3) & 63, m = (idx >> 9) & 1, t = idx >> 10;
    int co  = (l & 31) + 32 * m;
    int cin = 8 * (l >> 5) + e;
    wpk[idx] = (_Float16)w[((co * CIN + cin) * 3 + t / 3) * 3 + (t % 3)];
}

__device__ __forceinline__ float tanh_fast(float v) {
    float e = __expf(2.0f * v);
    return 1.0f - 2.0f * __builtin_amdgcn_rcpf(e + 1.0f);
}
__device__ __forceinline__ float min3f(float a, float b, float c) {
    return fminf(fminf(a, b), c);   // clang fuses to v_min3_f32
}

// 256 threads = 4 waves; block = 32-row strip x 256 px; 2 blocks/CU.
// Each wave owns px [64q, 64q+64) + 2-px halo, with a PRIVATE 4-row LDS ring.
// ZERO barriers: all ordering is within-wave program order (lgkm/vm counted).
__global__ __launch_bounds__(256, 2) void conv_mfma_kernel(
        const float* __restrict__ x, const f16x8* __restrict__ wpk,
        const float* __restrict__ bias, float* __restrict__ out) {
    // per wave: 4 row-slots x (132 main + 4 halo) f16x8 = 8.5 KB; x4 waves.
    __shared__ f16x8 xs[4 * 4 * 136];

    const int tid  = threadIdx.x;
    const int lane = tid & 63;
    const int wave = tid >> 6;
    const int b    = blockIdx.x >> 3;           // image
    const int s    = blockIdx.x & 7;            // 32-row strip
    const int oh0  = s * STRIP;
    const int P    = wave * 64;                 // wave's pixel base

    const float* xb = x + (size_t)b * CIN * H * W;

    // ---- weights: global -> 72 VGPRs (loop-invariant) ----
    f16x8 wreg[NTAP][2];
#pragma unroll
    for (int t = 0; t < NTAP; ++t)
#pragma unroll
        for (int m = 0; m < 2; ++m)
            wreg[t][m] = wpk[(t * 2 + m) * 64 + lane];

    const int l31 = lane & 31;
    const int g2  = lane >> 5;
    const int px2 = 2 * l31;                    // staged pixel pair (wave-rel)

    f16x8*    xw  = xs + wave * 544;            // wave-private region
    _Float16* xwh = (_Float16*)xw;              // f16 view for halo writes

    const int wr0 = XS(px2, g2);
    const int wr1 = XS(px2 + 1, g2);
    // halo: lanes 0..31 stage px P+64+(l&1), cin l>>1
    const bool hsel = (lane < 32);
    int hpx = P + 64 + (lane & 1); if (hpx > 255) hpx = 255;
    const int hcin = (lane & 31) >> 1;
    const int hoff = 1056 + (lane & 1) * 16 + hcin;   // f16 units in row region

    // fragment slot offsets (wave-rel px; halo area for px >= 64)
    int off[3][2];
#pragma unroll
    for (int kw = 0; kw < 3; ++kw)
#pragma unroll
        for (int n = 0; n < 2; ++n) {
            int px = 32 * n + l31 + kw;
            off[kw][n] = (px < 64) ? XS(px, g2) : (132 + (px - 64) * 2 + g2);
        }

    // bias as MFMA C-fragment: col=l31(px), row=(r&3)+8*(r>>2)+4*g2+32m (co)
    f32x16 cbias[2];
#pragma unroll
    for (int m = 0; m < 2; ++m)
#pragma unroll
        for (int r = 0; r < 16; ++r)
            cbias[m][r] = bias[(r & 3) + 8 * (r >> 2) + 4 * g2 + 32 * m];

    float2 vv[8];
    float  vh;

#define SLOAD(rowAbs)                                                           \
    {                                                                           \
        int r_ = (rowAbs) > 255 ? 255 : (rowAbs);                               \
        const float* p_ = xb + (size_t)r_ * W;                                  \
        _Pragma("unroll")                                                       \
        for (int c = 0; c < 8; ++c)                                             \
            vv[c] = *(const float2*)(p_ + (size_t)(8 * g2 + c) * (H * W) + P + px2); \
        if (hsel) vh = p_[(size_t)hcin * (H * W) + hpx];                        \
    }

#define SWRITE(slot)                                                            \
    {                                                                           \
        f16x8 q0, q1;                                                           \
        _Pragma("unroll")                                                       \
        for (int c = 0; c < 8; ++c) { q0[c] = (_Float16)vv[c].x;                \
                                      q1[c] = (_Float16)vv[c].y; }              \
        xw[(slot) * 136 + wr0] = q0;                                            \
        xw[(slot) * 136 + wr1] = q1;                                            \
        if (hsel) xwh[(slot) * 1088 + hoff] = (_Float16)vh;                     \
    }

    // ---- prologue: rows 0..2 -> slots 0..2; row 3 left in flight ----
    SLOAD(oh0 + 0) SWRITE(0)
    SLOAD(oh0 + 1) SWRITE(1)
    SLOAD(oh0 + 2) SWRITE(2)
    SLOAD(oh0 + 3)

#pragma unroll 1
    for (int r = 0; r < STRIP; ++r) {
        const f16x8* xr0 = xw + ((r    ) & 3) * 136;
        const f16x8* xr1 = xw + ((r + 1) & 3) * 136;
        const f16x8* xr2 = xw + ((r + 2) & 3) * 136;

        f32x16 acc[2][2];
        // kh = 0,1 taps (rows r, r+1 — written >=2 iters ago)
#pragma unroll
        for (int t = 0; t < 6; ++t) {
            const int kw = t % 3;
            const f16x8* xr = (t < 3) ? xr0 : xr1;
#pragma unroll
            for (int n = 0; n < 2; ++n) {
                f16x8 bf = xr[off[kw][n]];
                if (t == 0) {
                    acc[0][n] = __builtin_amdgcn_mfma_f32_32x32x16_f16(wreg[0][0], bf, cbias[0], 0, 0, 0);
                    acc[1][n] = __builtin_amdgcn_mfma_f32_32x32x16_f16(wreg[0][1], bf, cbias[1], 0, 0, 0);
                } else {
                    acc[0][n] = __builtin_amdgcn_mfma_f32_32x32x16_f16(wreg[t][0], bf, acc[0][n], 0, 0, 0);
                    acc[1][n] = __builtin_amdgcn_mfma_f32_32x32x16_f16(wreg[t][1], bf, acc[1][n], 0, 0, 0);
                }
            }
        }

        // ring-write row r+3 (consumed next iter — cross-iter lgkm slack)
        SWRITE((r + 3) & 3)

        // kh = 2 taps (row r+2 — written last iter)
#pragma unroll
        for (int t = 6; t < 9; ++t) {
            const int kw = t % 3;
#pragma unroll
            for (int n = 0; n < 2; ++n) {
                f16x8 bf = xr2[off[kw][n]];
                acc[0][n] = __builtin_amdgcn_mfma_f32_32x32x16_f16(wreg[t][0], bf, acc[0][n], 0, 0, 0);
                acc[1][n] = __builtin_amdgcn_mfma_f32_32x32x16_f16(wreg[t][1], bf, acc[1][n], 0, 0, 0);
            }
        }

        // issue loads for row r+4 (full-iteration vmcnt window)
        SLOAD(oh0 + r + 4)

        // epilogue: min over 64 cout (min3 tree) -> tanh(tanh) -> store
        const int oh = oh0 + r;
#pragma unroll
        for (int n = 0; n < 2; ++n) {
            float tq[16];
#pragma unroll
            for (int q = 0; q < 16; ++q)
                tq[q] = fminf(acc[0][n][q], acc[1][n][q]);
            float a  = min3f(tq[0],  tq[1],  tq[2]);
            float b2 = min3f(tq[3],  tq[4],  tq[5]);
            float c  = min3f(tq[6],  tq[7],  tq[8]);
            float d  = min3f(tq[9],  tq[10], tq[11]);
            float e  = min3f(tq[12], tq[13], tq[14]);
            float mn = fminf(min3f(a, b2, c), min3f(d, e, tq[15]));
            mn = fminf(mn, __shfl_xor(mn, 32));
            float t2 = tanh_fast(tanh_fast(mn));
            int px = P + 32 * n + l31;
            if (g2 == 0 && px < OW && oh < OH)
                out[((size_t)b * OH + oh) * OW + px] = t2;
        }
    }
}

extern "C" void kernel_launch(void* const* d_in, const int* in_sizes, int n_in,
                              void* d_out, int out_size, void* d_ws, size_t ws_size,
                              hipStream_t stream) {
    const float* x    = (const float*)d_in[0];
    const float* w    = (const float*)d_in[1];
    const float* bias = (const float*)d_in[2];
    float* out = (float*)d_out;
    _Float16* wpk = (_Float16*)d_ws;   // 9216 fp16 = 18,432 B

    wpack_kernel<<<36, 256, 0, stream>>>(w, wpk);
    conv_mfma_kernel<<<64 * 8, 256, 0, stream>>>(x, (const f16x8*)wpk, bias, out);
}